// Round 2
// baseline (263.571 us; speedup 1.0000x reference)
//
#include <hip/hip_runtime.h>

#define NPZ 81
#define NNODES 20736
#define CH 128
#define NHEAD 4
#define NB 20
#define NLAY 8
#define TPB 512

typedef __attribute__((ext_vector_type(4))) float f32x4;
typedef __attribute__((ext_vector_type(8))) __bf16 bf16x8;
typedef __attribute__((ext_vector_type(8))) unsigned short u16x8;

__device__ __forceinline__ unsigned short f2bf(float f) {
  unsigned int u = __float_as_uint(f);
  u = (u + 0x7fffu + ((u >> 16) & 1u)) >> 16;
  return (unsigned short)u;
}

// ---------------- embedding gather ----------------
__global__ void k_embed(const int* __restrict__ x, const float* __restrict__ ew,
                        float* __restrict__ h) {
  const int tot = NNODES * (CH / 4);
  for (int i = blockIdx.x * blockDim.x + threadIdx.x; i < tot;
       i += gridDim.x * blockDim.x) {
    const int n = i >> 5, c4 = i & 31;
    const int xv = x[n];
    ((f32x4*)h)[i] = ((const f32x4*)ew)[xv * 32 + c4];
  }
}

// ---------------- pack Wl||Wr into MFMA B-fragment order, bf16 ----------------
// flat index t = ((l*16 + nt)*4 + kb)*64 + lane ; elem e: B[k][c],
// k = kb*32 + (lane>>4)*8 + e, c = nt*16 + (lane&15)
__global__ void k_pack(const float* __restrict__ Wl, const float* __restrict__ Wr,
                       u16x8* __restrict__ wpk) {
  const int t = blockIdx.x * blockDim.x + threadIdx.x;
  if (t >= NLAY * 16 * 4 * 64) return;
  const int lane = t & 63;
  const int kb = (t >> 6) & 3;
  const int nt = (t >> 8) & 15;
  const int l = t >> 12;
  const int cc = nt * 16 + (lane & 15);
  const int k0 = kb * 32 + (lane >> 4) * 8;
  const float* W = (cc < CH) ? (Wl + (size_t)l * CH * CH + cc)
                             : (Wr + (size_t)l * CH * CH + (cc - CH));
  u16x8 v;
#pragma unroll
  for (int e = 0; e < 8; ++e) v[e] = f2bf(W[(size_t)(k0 + e) * CH]);
  wpk[t] = v;
}

// ---------------- fused layer kernel: LN(prev) + GEMM + GATv2 edge ----------------
__launch_bounds__(TPB)
__global__ void k_layer(const int layer,
                        float* __restrict__ h,    // [N,C] residual stream (in/out)
                        float* __restrict__ out,  // [N,C] conv output (prev in / new out)
                        const u16x8* __restrict__ wpk,
                        const float* __restrict__ bl, const float* __restrict__ br,
                        const float* __restrict__ att, const float* __restrict__ convb,
                        const float* __restrict__ lnw, const float* __restrict__ lnb,
                        float* __restrict__ partials)  // [NLAY][256][2]
{
  __shared__ unsigned short h_s[NPZ * 136];  // bf16 h rows, stride 136
  __shared__ float xl_s[NPZ * 128];          // swizzled float4 chunks
  __shared__ float xr_s[NPZ * 128];
  __shared__ int nb_s[NPZ * NB];
  __shared__ float att_s[CH], cvb_s[CH], bias_s[256];
  __shared__ float red_s[16];

  const int tid = threadIdx.x;
  const int pz = blockIdx.x;
  const int n0 = pz * NPZ;

  // ---- phase 1: neighbor lists + parameter staging ----
  if (tid < NPZ) {
    const int r = tid / 9, cq = tid % 9;
    int cnt = tid * NB;
    for (int k = 0; k < 9; ++k) if (k != cq) nb_s[cnt++] = r * 9 + k;
    for (int k = 0; k < 9; ++k) if (k != r) nb_s[cnt++] = k * 9 + cq;
    const int br0 = (r / 3) * 3, bc0 = (cq / 3) * 3;
    for (int i = br0; i < br0 + 3; ++i)
      for (int jj = bc0; jj < bc0 + 3; ++jj)
        if (i != r && jj != cq) nb_s[cnt++] = i * 9 + jj;
  }
  if (tid < 256) bias_s[tid] = (tid < CH) ? bl[layer * CH + tid] : br[layer * CH + tid - CH];
  if (tid >= 256 && tid < 384) att_s[tid - 256] = att[layer * CH + (tid - 256)];
  if (tid >= 384) cvb_s[tid - 384] = convb[layer * CH + (tid - 384)];

  // ---- phase 2: stats of prev layer + LN + residual + bf16 stage of h ----
  float mean = 0.f, inv = 0.f;
  if (layer > 0) {
    const int lane = tid & 63;
    float s1 = 0.f, s2 = 0.f;
#pragma unroll
    for (int i = 0; i < 4; ++i) {
      const float2 p = ((const float2*)partials)[(layer - 1) * 256 + lane + i * 64];
      s1 += p.x; s2 += p.y;
    }
#pragma unroll
    for (int mm = 1; mm < 64; mm <<= 1) {
      s1 += __shfl_xor(s1, mm, 64);
      s2 += __shfl_xor(s2, mm, 64);
    }
    const float M = (float)NNODES * CH;
    mean = s1 / M;
    const float var = fmaxf(s2 / M - mean * mean, 0.f);
    inv = 1.f / (sqrtf(var) + 1e-5f);
  }
  for (int idx = tid; idx < NPZ * CH; idx += TPB) {
    const int rr = idx >> 7, c = idx & 127;
    const size_t g = (size_t)(n0 + rr) * CH + c;
    float hv;
    if (layer == 0) {
      hv = h[g];
    } else {
      const float ov = out[g];
      const float gg = (ov - mean) * inv;
      hv = fmaxf(gg * lnw[(layer - 1) * CH + c] + lnb[(layer - 1) * CH + c], 0.f) + h[g];
      h[g] = hv;
    }
    h_s[rr * 136 + c] = f2bf(hv);
  }
  __syncthreads();

  // ---- phase 3: GEMM  [81x128] @ [128x256] -> xl||xr via MFMA ----
  {
    const int wv = tid >> 6, lane = tid & 63;
    const int l15 = lane & 15, l4 = lane >> 4;
    const int mtb = wv >> 2, ntb = wv & 3;
    bf16x8 bfr[4][4];
#pragma unroll
    for (int ni = 0; ni < 4; ++ni)
#pragma unroll
      for (int kb = 0; kb < 4; ++kb)
        bfr[ni][kb] = ((const bf16x8*)wpk)[(((size_t)layer * 16 + (ntb + ni * 4)) * 4 + kb) * 64 + lane];
#pragma unroll
    for (int mi = 0; mi < 3; ++mi) {
      const int mt = mtb + mi * 2;
      int arow = mt * 16 + l15; arow = arow > 80 ? 80 : arow;
      bf16x8 afr[4];
#pragma unroll
      for (int kb = 0; kb < 4; ++kb)
        afr[kb] = *(const bf16x8*)&h_s[arow * 136 + kb * 32 + l4 * 8];
#pragma unroll
      for (int ni = 0; ni < 4; ++ni) {
        f32x4 acc = {0.f, 0.f, 0.f, 0.f};
#pragma unroll
        for (int kb = 0; kb < 4; ++kb)
          acc = __builtin_amdgcn_mfma_f32_16x16x32_bf16(afr[kb], bfr[ni][kb], acc, 0, 0, 0);
        const int nt = ntb + ni * 4;
        const int cc = nt * 16 + l15;
        const float bia = bias_s[cc];
        float* dst = (cc < CH) ? xl_s : xr_s;
        const int c127 = cc & 127;
        const int hh = c127 >> 5;
        const int c4 = (c127 >> 2) & 7, el = c127 & 3;
#pragma unroll
        for (int i = 0; i < 4; ++i) {
          const int row = mt * 16 + l4 * 4 + i;
          if (row < NPZ)
            dst[row * 128 + (hh * 8 + (c4 ^ (row & 7))) * 4 + el] = acc[i] + bia;
        }
      }
    }
  }
  __syncthreads();

  // ---- phase 4: GATv2 attention, online softmax per (node, head) ----
  float psum = 0.f, psumsq = 0.f;
  if (tid < NPZ * NHEAD) {
    const int j = tid >> 2, hh = tid & 3;
    const int jx = j & 7;
    const int xb = hh * 8;
    f32x4 xr4[8], at4[8];
#pragma unroll
    for (int c4 = 0; c4 < 8; ++c4) {
      xr4[c4] = *(const f32x4*)&xr_s[j * 128 + (xb + (c4 ^ jx)) * 4];
      at4[c4] = *(const f32x4*)&att_s[hh * 32 + c4 * 4];
    }
    float m = -3.0e38f, ssum = 0.f;
    f32x4 oacc[8] = {};
    for (int k = 0; k < NB; ++k) {
      const int nbk = nb_s[j * NB + k];
      const int nx = nbk & 7;
      f32x4 v[8];
      float lg0 = 0.f, lg1 = 0.f, lg2 = 0.f, lg3 = 0.f;
#pragma unroll
      for (int c4 = 0; c4 < 8; ++c4) {
        v[c4] = *(const f32x4*)&xl_s[nbk * 128 + (xb + (c4 ^ nx)) * 4];
        const f32x4 s = v[c4] + xr4[c4];
        f32x4 u;
#pragma unroll
        for (int q = 0; q < 4; ++q) u[q] = fmaf(0.4f, fabsf(s[q]), 0.6f * s[q]);  // leaky_relu 0.2
        lg0 = fmaf(u[0], at4[c4][0], lg0);
        lg1 = fmaf(u[1], at4[c4][1], lg1);
        lg2 = fmaf(u[2], at4[c4][2], lg2);
        lg3 = fmaf(u[3], at4[c4][3], lg3);
      }
      const float lg = (lg0 + lg1) + (lg2 + lg3);
      const float nm = fmaxf(m, lg);
      const float sc = __expf(m - nm);
      const float e = __expf(lg - nm);
      ssum = fmaf(ssum, sc, e);
#pragma unroll
      for (int c4 = 0; c4 < 8; ++c4) oacc[c4] = oacc[c4] * sc + v[c4] * e;
      m = nm;
    }
    const float rs = 1.f / ssum;
    float* og = out + (size_t)(n0 + j) * CH + hh * 32;
#pragma unroll
    for (int c4 = 0; c4 < 8; ++c4) {
      const f32x4 o = oacc[c4] * rs + *(const f32x4*)&cvb_s[hh * 32 + c4 * 4];
      *(f32x4*)&og[c4 * 4] = o;
      psum += (o[0] + o[1]) + (o[2] + o[3]);
      psumsq += (o[0] * o[0] + o[1] * o[1]) + (o[2] * o[2] + o[3] * o[3]);
    }
  }

  // ---- phase 5: block stats reduction -> partials[layer][pz] ----
#pragma unroll
  for (int mm = 1; mm < 64; mm <<= 1) {
    psum += __shfl_xor(psum, mm, 64);
    psumsq += __shfl_xor(psumsq, mm, 64);
  }
  if ((tid & 63) == 0) { red_s[(tid >> 6) * 2] = psum; red_s[(tid >> 6) * 2 + 1] = psumsq; }
  __syncthreads();
  if (tid == 0) {
    float a = 0.f, b = 0.f;
#pragma unroll
    for (int i = 0; i < 8; ++i) { a += red_s[i * 2]; b += red_s[i * 2 + 1]; }
    ((float2*)partials)[layer * 256 + pz] = make_float2(a, b);
  }
}

// ---------------- final LN + classifier ----------------
__global__ void k_cls(const float* __restrict__ h, const float* __restrict__ out,
                      const float* __restrict__ lnw, const float* __restrict__ lnb,
                      const float* __restrict__ clsw, const float* __restrict__ clsb,
                      const float* __restrict__ partials, float* __restrict__ logits) {
  __shared__ float h_s[64 * 132];
  __shared__ float w_s[CH * 12];
  __shared__ float b_s[9];
  const int tid = threadIdx.x;
  const int nb0 = blockIdx.x * 64;
  const int lane = tid & 63;
  float s1 = 0.f, s2 = 0.f;
#pragma unroll
  for (int i = 0; i < 4; ++i) {
    const float2 p = ((const float2*)partials)[7 * 256 + lane + i * 64];
    s1 += p.x; s2 += p.y;
  }
#pragma unroll
  for (int mm = 1; mm < 64; mm <<= 1) {
    s1 += __shfl_xor(s1, mm, 64);
    s2 += __shfl_xor(s2, mm, 64);
  }
  const float M = (float)NNODES * CH;
  const float mean = s1 / M;
  const float var = fmaxf(s2 / M - mean * mean, 0.f);
  const float inv = 1.f / (sqrtf(var) + 1e-5f);

  for (int idx = tid; idx < 64 * CH; idx += 256) {
    const int rr = idx >> 7, c = idx & 127;
    const size_t g = (size_t)(nb0 + rr) * CH + c;
    const float gg = (out[g] - mean) * inv;
    h_s[rr * 132 + c] = fmaxf(gg * lnw[7 * CH + c] + lnb[7 * CH + c], 0.f) + h[g];
  }
  for (int idx = tid; idx < CH * 9; idx += 256) {
    const int k = idx / 9, c = idx - k * 9;
    w_s[k * 12 + c] = clsw[k * 9 + c];
  }
  if (tid < 9) b_s[tid] = clsb[tid];
  __syncthreads();

  for (int t = tid; t < 64 * 9; t += 256) {
    const int rr = t / 9, cc = t - rr * 9;
    float a0 = 0.f, a1 = 0.f, a2 = 0.f, a3 = 0.f;
#pragma unroll 8
    for (int k = 0; k < CH; k += 4) {
      a0 = fmaf(h_s[rr * 132 + k + 0], w_s[(k + 0) * 12 + cc], a0);
      a1 = fmaf(h_s[rr * 132 + k + 1], w_s[(k + 1) * 12 + cc], a1);
      a2 = fmaf(h_s[rr * 132 + k + 2], w_s[(k + 2) * 12 + cc], a2);
      a3 = fmaf(h_s[rr * 132 + k + 3], w_s[(k + 3) * 12 + cc], a3);
    }
    logits[(size_t)(nb0 + rr) * 9 + cc] = b_s[cc] + (a0 + a1) + (a2 + a3);
  }
}

// ---------------- launcher ----------------
extern "C" void kernel_launch(void* const* d_in, const int* in_sizes, int n_in,
                              void* d_out, int out_size, void* d_ws, size_t ws_size,
                              hipStream_t stream) {
  const int* x = (const int*)d_in[0];
  // d_in[1] = edge_index: unused (fixed sudoku adjacency recomputed in-kernel)
  const float* ew = (const float*)d_in[2];
  const float* Wl = (const float*)d_in[3];
  const float* bl = (const float*)d_in[4];
  const float* Wr = (const float*)d_in[5];
  const float* br = (const float*)d_in[6];
  const float* att = (const float*)d_in[7];
  const float* cvb = (const float*)d_in[8];
  const float* lnw = (const float*)d_in[9];
  const float* lnb = (const float*)d_in[10];
  const float* clsw = (const float*)d_in[11];
  const float* clsb = (const float*)d_in[12];

  char* ws = (char*)d_ws;
  const size_t HB = (size_t)NNODES * CH * 4;  // 10,616,832
  float* h = (float*)ws;
  float* out = (float*)(ws + HB);
  u16x8* wpk = (u16x8*)(ws + 2 * HB);
  float* partials = (float*)(ws + 2 * HB + 524288);

  k_embed<<<1296, 256, 0, stream>>>(x, ew, h);
  k_pack<<<128, 256, 0, stream>>>(Wl, Wr, wpk);
  for (int l = 0; l < NLAY; ++l)
    k_layer<<<256, TPB, 0, stream>>>(l, h, out, wpk, bl, br, att, cvb, lnw, lnb, partials);
  k_cls<<<NNODES / 64, 256, 0, stream>>>(h, out, lnw, lnb, clsw, clsb, partials, (float*)d_out);
}